// Round 1
// baseline (210.074 us; speedup 1.0000x reference)
//
#include <hip/hip_runtime.h>
#include <math.h>

#define NQ 12
#define DIM 4096
#define KS 6
#define BB 256
#define SEQ 128
#define DEMB 512

// ---------------- Kernel 1: encoder (embed -> masked mean -> tanh proj) -----
__global__ __launch_bounds__(512) void enc_kernel(
    const int* __restrict__ ids, const int* __restrict__ mask,
    const float* __restrict__ emb, const float* __restrict__ pw,
    const float* __restrict__ pb, float* __restrict__ xout)
{
    int b = blockIdx.x;
    int tid = threadIdx.x;
    __shared__ float s_pool[DEMB];
    const int* idrow = ids + b * SEQ;
    const int* mrow  = mask + b * SEQ;
    float acc = 0.f, msum = 0.f;
    for (int s = 0; s < SEQ; ++s) {
        int m = mrow[s];
        if (m) {
            float fm = (float)m;
            int id = idrow[s];
            acc  += fm * emb[(size_t)id * DEMB + tid];
            msum += fm;
        }
    }
    s_pool[tid] = acc / fmaxf(msum, 1.f);
    __syncthreads();
    if (tid < NQ) {
        const float* w = pw + tid * DEMB;
        float d = pb[tid];
        for (int i = 0; i < DEMB; ++i) d = fmaf(s_pool[i], w[i], d);
        xout[b * NQ + tid] = tanhf(d) * 3.14159274101257324f;
    }
}

// ---------------- Kernel 2: statevector sim, one sample per block ----------
// State (4096 complex) lives in LDS. Per step: 12 fused (Rot*RY) gates,
// CNOT ring folded into ONE permutation, then Z expvals.
__global__ __launch_bounds__(512) void qsim_kernel(
    const float* __restrict__ x, const float* __restrict__ theta,
    float* __restrict__ readouts /* [K,B,NQ] */)
{
    __shared__ float s_re[DIM];
    __shared__ float s_im[DIM];
    __shared__ float s_u[NQ][8];
    __shared__ unsigned short s_perm[DIM];
    __shared__ float s_red[8][NQ];

    int b = blockIdx.x;
    int tid = threadIdx.x;

    // init state |0...0> and precompute CNOT-ring permutation:
    // out_w = b0^...^bw (w=1..11), out_0 = b1^...^b11 ; wire w <-> bit (11-w)
    for (int j = tid; j < DIM; j += 512) {
        s_re[j] = (j == 0) ? 1.f : 0.f;
        s_im[j] = 0.f;
        int b0 = (j >> 11) & 1;
        int pref = b0;
        int out = 0;
        for (int w = 1; w < NQ; ++w) {
            pref ^= (j >> (11 - w)) & 1;
            out |= pref << (11 - w);
        }
        out |= (b0 ^ pref) << 11;
        s_perm[j] = (unsigned short)out;
    }

    for (int k = 0; k < KS; ++k) {
        // fused U = Rot(phi,theta,omega) @ RY(x)
        if (tid < NQ) {
            float ang = x[b * NQ + tid];
            float cy = cosf(0.5f * ang), sy = sinf(0.5f * ang);
            const float* th = theta + (k * NQ + tid) * 3;
            float phi = th[0], te = th[1], om = th[2];
            float ct = cosf(0.5f * te), st = sinf(0.5f * te);
            float a1 = -0.5f * (phi + om);
            float epr = cosf(a1), epi = sinf(a1);   // ep = e^{-i(phi+om)/2}
            float a2 = 0.5f * (phi - om);
            float emr = cosf(a2), emi = sinf(a2);   // em = e^{ i(phi-om)/2}
            float R00r = epr * ct,  R00i = epi * ct;
            float R01r = -emr * st, R01i = -emi * st;
            float R10r = emr * st,  R10i = -emi * st;   // conj(em)*st
            float R11r = epr * ct,  R11i = -epi * ct;   // conj(ep)*ct
            s_u[tid][0] =  R00r * cy + R01r * sy;
            s_u[tid][1] =  R00i * cy + R01i * sy;
            s_u[tid][2] = -R00r * sy + R01r * cy;
            s_u[tid][3] = -R00i * sy + R01i * cy;
            s_u[tid][4] =  R10r * cy + R11r * sy;
            s_u[tid][5] =  R10i * cy + R11i * sy;
            s_u[tid][6] = -R10r * sy + R11r * cy;
            s_u[tid][7] = -R10i * sy + R11i * cy;
        }
        __syncthreads();

        // 12 fused single-qubit gates
        for (int w = 0; w < NQ; ++w) {
            int p = 11 - w;          // bit position of wire w
            int gap = 1 << p;
            float u00r = s_u[w][0], u00i = s_u[w][1];
            float u01r = s_u[w][2], u01i = s_u[w][3];
            float u10r = s_u[w][4], u10i = s_u[w][5];
            float u11r = s_u[w][6], u11i = s_u[w][7];
            #pragma unroll
            for (int r = 0; r < 4; ++r) {
                int t = tid + 512 * r;                     // pair index [0,2048)
                int j0 = ((t >> p) << (p + 1)) | (t & (gap - 1));
                int j1 = j0 + gap;
                float a0r = s_re[j0], a0i = s_im[j0];
                float a1r = s_re[j1], a1i = s_im[j1];
                s_re[j0] = u00r * a0r - u00i * a0i + u01r * a1r - u01i * a1i;
                s_im[j0] = u00r * a0i + u00i * a0r + u01r * a1i + u01i * a1r;
                s_re[j1] = u10r * a0r - u10i * a0i + u11r * a1r - u11i * a1i;
                s_im[j1] = u10r * a0i + u10i * a0r + u11r * a1i + u11i * a1r;
            }
            __syncthreads();
        }

        // CNOT ring = one permutation: read-all, sync, scatter
        {
            float vr[8], vi[8];
            int dj[8];
            #pragma unroll
            for (int r = 0; r < 8; ++r) {
                int j = tid + 512 * r;
                vr[r] = s_re[j]; vi[r] = s_im[j];
                dj[r] = s_perm[j];
            }
            __syncthreads();
            #pragma unroll
            for (int r = 0; r < 8; ++r) {
                s_re[dj[r]] = vr[r];
                s_im[dj[r]] = vi[r];
            }
            __syncthreads();
        }

        // Z expvals: <Z_i> = sum_j p_j * (1 - 2*bit_{11-i}(j))
        {
            float z[NQ];
            #pragma unroll
            for (int i = 0; i < NQ; ++i) z[i] = 0.f;
            #pragma unroll
            for (int r = 0; r < 8; ++r) {
                int j = tid + 512 * r;
                float pr = s_re[j] * s_re[j] + s_im[j] * s_im[j];
                #pragma unroll
                for (int i = 0; i < NQ; ++i)
                    z[i] += ((j >> (11 - i)) & 1) ? -pr : pr;
            }
            #pragma unroll
            for (int i = 0; i < NQ; ++i) {
                #pragma unroll
                for (int off = 32; off > 0; off >>= 1)
                    z[i] += __shfl_down(z[i], off, 64);
            }
            int wave = tid >> 6, lane = tid & 63;
            if (lane == 0)
                for (int i = 0; i < NQ; ++i) s_red[wave][i] = z[i];
            __syncthreads();
            if (tid < NQ) {
                float s = 0.f;
                for (int w2 = 0; w2 < 8; ++w2) s += s_red[w2][tid];
                readouts[(k * BB + b) * NQ + tid] = s;
            }
            __syncthreads();
        }
    }
}

// ---------------- Kernel 3: head (logits + duplicated last step) -----------
__global__ void head_kernel(const float* __restrict__ readouts,
                            const float* __restrict__ hw,
                            const float* __restrict__ hb,
                            float* __restrict__ logits,
                            float* __restrict__ last)
{
    int idx = blockIdx.x * 256 + threadIdx.x;   // [0, 6*256*8)
    if (idx >= KS * BB * 8) return;
    int c = idx & 7;
    int kb = idx >> 3;                          // k*256 + b
    const float* r = readouts + kb * NQ;
    float acc = hb[c];
    #pragma unroll
    for (int i = 0; i < NQ; ++i) acc = fmaf(r[i], hw[c * NQ + i], acc);
    logits[idx] = acc;
    if (kb >= (KS - 1) * BB) last[(kb - (KS - 1) * BB) * 8 + c] = acc;
}

extern "C" void kernel_launch(void* const* d_in, const int* in_sizes, int n_in,
                              void* d_out, int out_size, void* d_ws, size_t ws_size,
                              hipStream_t stream) {
    const int*   ids   = (const int*)d_in[0];
    const int*   mask  = (const int*)d_in[1];
    const float* emb   = (const float*)d_in[2];
    const float* pw    = (const float*)d_in[3];
    const float* pb    = (const float*)d_in[4];
    const float* theta = (const float*)d_in[5];
    const float* hw    = (const float*)d_in[6];
    const float* hb    = (const float*)d_in[7];
    float* out = (float*)d_out;

    float* x = (float*)d_ws;                         // [B, NQ]
    float* readouts = out + KS * BB * 8;             // [K,B,NQ] region of d_out
    float* last     = out + KS * BB * 8 + KS * BB * NQ;

    enc_kernel<<<BB, 512, 0, stream>>>(ids, mask, emb, pw, pb, x);
    qsim_kernel<<<BB, 512, 0, stream>>>(x, theta, readouts);
    head_kernel<<<(KS * BB * 8 + 255) / 256, 256, 0, stream>>>(readouts, hw, hb, out, last);
}

// Round 2
// 159.997 us; speedup vs baseline: 1.3130x; 1.3130x over previous
//
#include <hip/hip_runtime.h>
#include <math.h>

#define NQ 12
#define DIM 4096
#define KS 6
#define BB 256
#define SEQ 128
#define DEMB 512

// ---------------- Kernel 1: encoder (embed -> masked mean -> tanh proj) -----
__global__ __launch_bounds__(512) void enc_kernel(
    const int* __restrict__ ids, const int* __restrict__ mask,
    const float* __restrict__ emb, const float* __restrict__ pw,
    const float* __restrict__ pb, float* __restrict__ xout)
{
    int b = blockIdx.x;
    int tid = threadIdx.x;
    int g = tid >> 7, e = tid & 127;

    __shared__ int   s_ids[SEQ];
    __shared__ float s_m[SEQ];
    __shared__ float4 s_part[4][128];
    __shared__ float s_msum[4];
    __shared__ float s_wred[2][NQ];

    if (tid < SEQ) {
        s_ids[tid] = ids[b * SEQ + tid];
        s_m[tid]   = (float)mask[b * SEQ + tid];
    }
    __syncthreads();

    // gather-accumulate: group g handles seq positions s = g, g+4, ...
    float4 acc = make_float4(0.f, 0.f, 0.f, 0.f);
    float msum = 0.f;
    for (int s = g; s < SEQ; s += 4) {
        float m = s_m[s];
        if (m != 0.f) {
            float4 v = ((const float4*)emb)[(size_t)s_ids[s] * 128 + e];
            acc.x += m * v.x; acc.y += m * v.y;
            acc.z += m * v.z; acc.w += m * v.w;
            msum += m;
        }
    }
    s_part[g][e] = acc;
    if (e == 0) s_msum[g] = msum;
    __syncthreads();

    // threads 0..127: finish pooling, 12 dots, wave-shuffle reduce
    if (tid < 128) {
        float tm = fmaxf(s_msum[0] + s_msum[1] + s_msum[2] + s_msum[3], 1.f);
        float inv = 1.f / tm;
        float4 p0 = s_part[0][tid], p1 = s_part[1][tid];
        float4 p2 = s_part[2][tid], p3 = s_part[3][tid];
        float4 p;
        p.x = (p0.x + p1.x + p2.x + p3.x) * inv;
        p.y = (p0.y + p1.y + p2.y + p3.y) * inv;
        p.z = (p0.z + p1.z + p2.z + p3.z) * inv;
        p.w = (p0.w + p1.w + p2.w + p3.w) * inv;

        float z[NQ];
        #pragma unroll
        for (int i = 0; i < NQ; ++i) {
            float4 w4 = ((const float4*)pw)[i * 128 + tid];
            z[i] = p.x * w4.x + p.y * w4.y + p.z * w4.z + p.w * w4.w;
        }
        #pragma unroll
        for (int i = 0; i < NQ; ++i) {
            #pragma unroll
            for (int off = 32; off > 0; off >>= 1)
                z[i] += __shfl_xor(z[i], off, 64);
        }
        if ((tid & 63) == 0) {
            int w = tid >> 6;
            #pragma unroll
            for (int i = 0; i < NQ; ++i) s_wred[w][i] = z[i];
        }
    }
    __syncthreads();
    if (tid < NQ) {
        float d = pb[tid] + s_wred[0][tid] + s_wred[1][tid];
        xout[b * NQ + tid] = tanhf(d) * 3.14159274101257324f;
    }
}

// ---------------- Kernel 2: register-resident statevector sim + head -------
// 512 threads, 8 complex amps/thread. Layout A: j = tid*8 + r
//   j bits 0-2 = r, bits 3-8 = lane, bits 9-11 = wave.
// Per step: 3 register gates + 6 shuffle gates, LDS transpose (bits 0-2 <->
// 9-11), 3 register gates, ring-permutation scatter back to layout A,
// expvals + head from registers. LDS addresses XOR-swizzled: phys = j^((j>>6)&7).

#define REG_GATE(P, W) { \
    const float* u = &s_u[k][W][0]; \
    float u00r=u[0],u00i=u[1],u01r=u[2],u01i=u[3]; \
    float u10r=u[4],u10i=u[5],u11r=u[6],u11i=u[7]; \
    _Pragma("unroll") \
    for (int r0 = 0; r0 < 8; ++r0) if (!(r0 & (1 << (P)))) { \
        int r1 = r0 | (1 << (P)); \
        float2 A = a[r0], Bv = a[r1]; \
        a[r0].x = u00r*A.x - u00i*A.y + u01r*Bv.x - u01i*Bv.y; \
        a[r0].y = u00r*A.y + u00i*A.x + u01r*Bv.y + u01i*Bv.x; \
        a[r1].x = u10r*A.x - u10i*A.y + u11r*Bv.x - u11i*Bv.y; \
        a[r1].y = u10r*A.y + u10i*A.x + u11r*Bv.y + u11i*Bv.x; \
    } }

__global__ __launch_bounds__(512) void qsim_kernel(
    const float* __restrict__ x, const float* __restrict__ theta,
    const float* __restrict__ hw, const float* __restrict__ hb,
    float* __restrict__ readouts, float* __restrict__ logits,
    float* __restrict__ last)
{
    __shared__ float2 buf0[DIM];          // 32 KB
    __shared__ float2 buf1[DIM];          // 32 KB
    __shared__ float  s_u[KS][NQ][8];     // all fused gate matrices
    __shared__ float  s_red[8][NQ];
    __shared__ float  s_rd[NQ];

    int b = blockIdx.x;
    int tid = threadIdx.x;
    int lane = tid & 63, wave = tid >> 6;

    // precompute all K*NQ fused U = Rot(phi,te,om) @ RY(ang)
    for (int t = tid; t < KS * NQ; t += 512) {
        int k = t / NQ, w = t % NQ;
        float ang = x[b * NQ + w];
        float cy = cosf(0.5f * ang), sy = sinf(0.5f * ang);
        const float* th = theta + (k * NQ + w) * 3;
        float phi = th[0], te = th[1], om = th[2];
        float ct = cosf(0.5f * te), st = sinf(0.5f * te);
        float a1 = -0.5f * (phi + om);
        float epr = cosf(a1), epi = sinf(a1);
        float a2 = 0.5f * (phi - om);
        float emr = cosf(a2), emi = sinf(a2);
        float R00r = epr * ct,  R00i = epi * ct;
        float R01r = -emr * st, R01i = -emi * st;
        float R10r = emr * st,  R10i = -emi * st;
        float R11r = epr * ct,  R11i = -epi * ct;
        s_u[k][w][0] =  R00r * cy + R01r * sy;
        s_u[k][w][1] =  R00i * cy + R01i * sy;
        s_u[k][w][2] = -R00r * sy + R01r * cy;
        s_u[k][w][3] = -R00i * sy + R01i * cy;
        s_u[k][w][4] =  R10r * cy + R11r * sy;
        s_u[k][w][5] =  R10i * cy + R11i * sy;
        s_u[k][w][6] = -R10r * sy + R11r * cy;
        s_u[k][w][7] = -R10i * sy + R11i * cy;
    }

    // constant-across-steps address precompute
    int cA = (tid >> 3) & 7;          // SW bits for layout-A block
    int baseA = tid * 8;
    int cB = (lane >> 3) & 7;         // SW bits for layout-B reads
    int baseB = (lane << 3) | (wave ^ cB);
    int idxP[8];                      // swizzled ring-perm targets (layout B src)
    #pragma unroll
    for (int rb = 0; rb < 8; ++rb) {
        int jp = (rb << 9) | (lane << 3) | wave;
        int b0 = (jp >> 11) & 1;
        int pref = b0, outv = 0;
        for (int w = 1; w < NQ; ++w) {
            pref ^= (jp >> (11 - w)) & 1;
            outv |= pref << (11 - w);
        }
        outv |= (b0 ^ pref) << 11;
        idxP[rb] = outv ^ ((outv >> 6) & 7);
    }

    // init |0...0>: j=0 amplitude 1 (thread 0, r=0)
    float2 a[8];
    #pragma unroll
    for (int r = 0; r < 8; ++r) a[r] = make_float2(0.f, 0.f);
    if (tid == 0) a[0].x = 1.f;
    __syncthreads();   // s_u ready

    for (int k = 0; k < KS; ++k) {
        // --- gates on register bits (wires 11,10,9) ---
        REG_GATE(0, 11)
        REG_GATE(1, 10)
        REG_GATE(2, 9)

        // --- gates on lane bits q=p-3 (wires 8..3) ---
        #pragma unroll
        for (int p = 3; p <= 8; ++p) {
            const float* u = &s_u[k][11 - p][0];
            int q = p - 3, mk = 1 << q;
            int bit = (lane >> q) & 1;
            float c0r = bit ? u[6] : u[0];
            float c0i = bit ? u[7] : u[1];
            float c1r = bit ? u[4] : u[2];
            float c1i = bit ? u[5] : u[3];
            #pragma unroll
            for (int r = 0; r < 8; ++r) {
                float px = __shfl_xor(a[r].x, mk, 64);
                float py = __shfl_xor(a[r].y, mk, 64);
                float nx = c0r * a[r].x - c0i * a[r].y + c1r * px - c1i * py;
                float ny = c0r * a[r].y + c0i * a[r].x + c1r * py + c1i * px;
                a[r].x = nx; a[r].y = ny;
            }
        }

        // --- transpose A->B (swap j bits 0-2 with 9-11) ---
        #pragma unroll
        for (int r = 0; r < 8; ++r) buf0[baseA + (r ^ cA)] = a[r];
        __syncthreads();
        #pragma unroll
        for (int rb = 0; rb < 8; ++rb) a[rb] = buf0[(rb << 9) | baseB];

        // --- gates on former wave bits (wires 2,1,0) ---
        REG_GATE(0, 2)
        REG_GATE(1, 1)
        REG_GATE(2, 0)

        // --- CNOT ring permutation scatter back to layout A ---
        #pragma unroll
        for (int rb = 0; rb < 8; ++rb) buf1[idxP[rb]] = a[rb];
        __syncthreads();
        #pragma unroll
        for (int r = 0; r < 8; ++r) a[r] = buf1[baseA + (r ^ cA)];

        // --- expvals ---
        float pr[8];
        #pragma unroll
        for (int r = 0; r < 8; ++r)
            pr[r] = a[r].x * a[r].x + a[r].y * a[r].y;
        float T = pr[0]+pr[1]+pr[2]+pr[3]+pr[4]+pr[5]+pr[6]+pr[7];
        float z[NQ];
        z[11] = (pr[0]-pr[1]) + (pr[2]-pr[3]) + (pr[4]-pr[5]) + (pr[6]-pr[7]);
        z[10] = (pr[0]+pr[1]) - (pr[2]+pr[3]) + (pr[4]+pr[5]) - (pr[6]+pr[7]);
        z[9]  = (pr[0]+pr[1]+pr[2]+pr[3]) - (pr[4]+pr[5]+pr[6]+pr[7]);
        #pragma unroll
        for (int w = 3; w <= 8; ++w)
            z[w] = ((lane >> (8 - w)) & 1) ? -T : T;
        // butterfly wires 3..11 and total T
        #pragma unroll
        for (int w = 3; w < NQ; ++w) {
            #pragma unroll
            for (int off = 32; off > 0; off >>= 1)
                z[w] += __shfl_xor(z[w], off, 64);
        }
        #pragma unroll
        for (int off = 32; off > 0; off >>= 1)
            T += __shfl_xor(T, off, 64);
        if (lane == 0) {
            #pragma unroll
            for (int w = 3; w < NQ; ++w) s_red[wave][w] = z[w];
            s_red[wave][0] = ((wave >> 2) & 1) ? -T : T;
            s_red[wave][1] = ((wave >> 1) & 1) ? -T : T;
            s_red[wave][2] = (wave & 1) ? -T : T;
        }
        __syncthreads();
        if (tid < NQ) {
            float s = 0.f;
            #pragma unroll
            for (int w2 = 0; w2 < 8; ++w2) s += s_red[w2][tid];
            s_rd[tid] = s;
            readouts[(k * BB + b) * NQ + tid] = s;
        }
        __syncthreads();
        if (tid < 8) {
            float acc2 = hb[tid];
            #pragma unroll
            for (int i = 0; i < NQ; ++i)
                acc2 = fmaf(s_rd[i], hw[tid * NQ + i], acc2);
            logits[(k * BB + b) * 8 + tid] = acc2;
            if (k == KS - 1) last[b * 8 + tid] = acc2;
        }
        // next step's first LDS write (buf0) is safe: last buf0 read was
        // before the post-scatter barrier; s_rd/s_red rewrites are behind
        // the next step's two barriers.
    }
}

extern "C" void kernel_launch(void* const* d_in, const int* in_sizes, int n_in,
                              void* d_out, int out_size, void* d_ws, size_t ws_size,
                              hipStream_t stream) {
    const int*   ids   = (const int*)d_in[0];
    const int*   mask  = (const int*)d_in[1];
    const float* emb   = (const float*)d_in[2];
    const float* pw    = (const float*)d_in[3];
    const float* pb    = (const float*)d_in[4];
    const float* theta = (const float*)d_in[5];
    const float* hw    = (const float*)d_in[6];
    const float* hb    = (const float*)d_in[7];
    float* out = (float*)d_out;

    float* xbuf     = (float*)d_ws;                  // [B, NQ]
    float* readouts = out + KS * BB * 8;             // [K,B,NQ]
    float* last     = out + KS * BB * 8 + KS * BB * NQ;

    enc_kernel<<<BB, 512, 0, stream>>>(ids, mask, emb, pw, pb, xbuf);
    qsim_kernel<<<BB, 512, 0, stream>>>(xbuf, theta, hw, hb, readouts, out, last);
}

// Round 3
// 145.731 us; speedup vs baseline: 1.4415x; 1.0979x over previous
//
#include <hip/hip_runtime.h>
#include <math.h>

#define NQ 12
#define DIM 4096
#define KS 6
#define BB 256
#define SEQ 128
#define DEMB 512

// Fused: encoder (embed->pool->tanh proj), 6-step VQC statevector sim,
// per-step Z-expvals and head. One block per sample, 512 threads.
//
// State layout A: j = tid*8 + r (bits 0-2 = reg, 3-8 = lane, 9-11 = wave).
// Per step: 3 reg gates + 6 shuffle gates (layout A), LDS transpose to
// layout B (bits 0-2 <-> 9-11), 3 reg gates, expvals computed PRE-scatter
// via prefix-XOR sign structure of the CNOT-ring permutation, then the ring
// scatter back to layout A. Only 2 __syncthreads per step.

#define REG_GATE(P, W) { \
    const float* u = &s_u[k][W][0]; \
    float u00r=u[0],u00i=u[1],u01r=u[2],u01i=u[3]; \
    float u10r=u[4],u10i=u[5],u11r=u[6],u11i=u[7]; \
    _Pragma("unroll") \
    for (int r0 = 0; r0 < 8; ++r0) if (!(r0 & (1 << (P)))) { \
        int r1 = r0 | (1 << (P)); \
        float2 A = a[r0], Bv = a[r1]; \
        a[r0].x = u00r*A.x - u00i*A.y + u01r*Bv.x - u01i*Bv.y; \
        a[r0].y = u00r*A.y + u00i*A.x + u01r*Bv.y + u01i*Bv.x; \
        a[r1].x = u10r*A.x - u10i*A.y + u11r*Bv.x - u11i*Bv.y; \
        a[r1].y = u10r*A.y + u10i*A.x + u11r*Bv.y + u11i*Bv.x; \
    } }

#define BF_PLAIN(v, m) { float p_ = __shfl_xor(v, m, 64); v = v + p_; }
#define BF_SIGN(v, m)  { float p_ = __shfl_xor(v, m, 64); float d_ = v - p_; \
                         v = (lane & m) ? -d_ : d_; }

__global__ __launch_bounds__(512) void fused_kernel(
    const int* __restrict__ ids, const int* __restrict__ mask,
    const float* __restrict__ emb, const float* __restrict__ pw,
    const float* __restrict__ pb, const float* __restrict__ theta,
    const float* __restrict__ hw, const float* __restrict__ hb,
    float* __restrict__ readouts, float* __restrict__ logits,
    float* __restrict__ last)
{
    __shared__ float2 buf0[DIM];          // 32 KB (also enc s_part)
    __shared__ float2 buf1[DIM];          // 32 KB (also enc s_ids/s_m)
    __shared__ float  s_u[KS][NQ][8];     // fused gate matrices, all steps
    __shared__ float  s_red[8][NQ];
    __shared__ float  s_msum[4];
    __shared__ float  s_wred[2][NQ];
    __shared__ float  s_x[NQ];
    __shared__ float  s_hw[8 * NQ];
    __shared__ float  s_hb[8];

    int b = blockIdx.x;
    int tid = threadIdx.x;
    int lane = tid & 63, wave = tid >> 6;

    // ---------------- encoder phase ----------------
    int*    s_ids = (int*)buf1;
    float*  s_m   = (float*)buf1 + SEQ;
    float4* s_part = (float4*)buf0;       // [4][128]

    if (tid < SEQ) {
        s_ids[tid] = ids[b * SEQ + tid];
        s_m[tid]   = (float)mask[b * SEQ + tid];
    }
    if (tid >= 256 && tid < 256 + 8 * NQ) s_hw[tid - 256] = hw[tid - 256];
    if (tid >= 384 && tid < 392)          s_hb[tid - 384] = hb[tid - 384];
    __syncthreads();

    {
        int g = tid >> 7, e = tid & 127;
        float4 acc = make_float4(0.f, 0.f, 0.f, 0.f);
        float msum = 0.f;
        #pragma unroll 4
        for (int s = g; s < SEQ; s += 4) {
            float m = s_m[s];
            float4 v = ((const float4*)emb)[(size_t)s_ids[s] * 128 + e];
            acc.x = fmaf(m, v.x, acc.x);
            acc.y = fmaf(m, v.y, acc.y);
            acc.z = fmaf(m, v.z, acc.z);
            acc.w = fmaf(m, v.w, acc.w);
            msum += m;
        }
        __syncthreads();   // s_ids/s_m reads done before buf0 overlay write
        s_part[g * 128 + e] = acc;
        if (e == 0) s_msum[g] = msum;
    }
    __syncthreads();

    if (tid < 128) {
        float tm = fmaxf(s_msum[0] + s_msum[1] + s_msum[2] + s_msum[3], 1.f);
        float inv = 1.f / tm;
        float4 p0 = s_part[0 * 128 + tid], p1 = s_part[1 * 128 + tid];
        float4 p2 = s_part[2 * 128 + tid], p3 = s_part[3 * 128 + tid];
        float4 p;
        p.x = (p0.x + p1.x + p2.x + p3.x) * inv;
        p.y = (p0.y + p1.y + p2.y + p3.y) * inv;
        p.z = (p0.z + p1.z + p2.z + p3.z) * inv;
        p.w = (p0.w + p1.w + p2.w + p3.w) * inv;
        float z[NQ];
        #pragma unroll
        for (int i = 0; i < NQ; ++i) {
            float4 w4 = ((const float4*)pw)[i * 128 + tid];
            z[i] = p.x * w4.x + p.y * w4.y + p.z * w4.z + p.w * w4.w;
        }
        #pragma unroll
        for (int i = 0; i < NQ; ++i) {
            #pragma unroll
            for (int off = 32; off > 0; off >>= 1)
                z[i] += __shfl_xor(z[i], off, 64);
        }
        if ((tid & 63) == 0) {
            int w = tid >> 6;
            #pragma unroll
            for (int i = 0; i < NQ; ++i) s_wred[w][i] = z[i];
        }
    }
    __syncthreads();
    if (tid < NQ) {
        float d = pb[tid] + s_wred[0][tid] + s_wred[1][tid];
        s_x[tid] = tanhf(d) * 3.14159274101257324f;
    }
    __syncthreads();

    // ---------------- gate matrices: U = Rot(phi,te,om) @ RY(x) ----------
    if (tid < KS * NQ) {
        int k = tid / NQ, w = tid % NQ;
        float ang = s_x[w];
        float cy = cosf(0.5f * ang), sy = sinf(0.5f * ang);
        const float* th = theta + (k * NQ + w) * 3;
        float phi = th[0], te = th[1], om = th[2];
        float ct = cosf(0.5f * te), st = sinf(0.5f * te);
        float a1 = -0.5f * (phi + om);
        float epr = cosf(a1), epi = sinf(a1);
        float a2 = 0.5f * (phi - om);
        float emr = cosf(a2), emi = sinf(a2);
        float R00r = epr * ct,  R00i = epi * ct;
        float R01r = -emr * st, R01i = -emi * st;
        float R10r = emr * st,  R10i = -emi * st;
        float R11r = epr * ct,  R11i = -epi * ct;
        s_u[k][w][0] =  R00r * cy + R01r * sy;
        s_u[k][w][1] =  R00i * cy + R01i * sy;
        s_u[k][w][2] = -R00r * sy + R01r * cy;
        s_u[k][w][3] = -R00i * sy + R01i * cy;
        s_u[k][w][4] =  R10r * cy + R11r * sy;
        s_u[k][w][5] =  R10i * cy + R11i * sy;
        s_u[k][w][6] = -R10r * sy + R11r * cy;
        s_u[k][w][7] = -R10i * sy + R11i * cy;
    }

    // ---------------- constant addresses ----------------
    int cA = (tid >> 3) & 7;              // swizzle bits, layout A
    int baseA = tid * 8;
    int cB = (lane >> 3) & 7;             // swizzle bits, layout B read
    int baseB = (lane << 3) | (wave ^ cB);
    int idxP[8];                          // ring-perm targets (swizzled)
    #pragma unroll
    for (int rb = 0; rb < 8; ++rb) {
        int jp = (rb << 9) | (lane << 3) | wave;
        int b0 = (jp >> 11) & 1;
        int pref = b0, outv = 0;
        for (int w = 1; w < NQ; ++w) {
            pref ^= (jp >> (11 - w)) & 1;
            outv |= pref << (11 - w);
        }
        outv |= (b0 ^ pref) << 11;
        idxP[rb] = outv ^ ((outv >> 6) & 7);
    }
    int wv2 = (wave >> 2) & 1, wv21 = ((wave >> 2) ^ (wave >> 1)) & 1;
    int wvp = ((wave >> 2) ^ (wave >> 1) ^ wave) & 1;   // parity(wave)

    float2 a[8];
    #pragma unroll
    for (int r = 0; r < 8; ++r) a[r] = make_float2(0.f, 0.f);
    if (tid == 0) a[0].x = 1.f;
    __syncthreads();   // s_u ready, buf reads done

    // ---------------- K steps ----------------
    for (int k = 0; k < KS; ++k) {
        // gates on register bits (wires 11,10,9), layout A
        REG_GATE(0, 11)
        REG_GATE(1, 10)
        REG_GATE(2, 9)

        // gates on lane bits (wires 8..3)
        #pragma unroll
        for (int p = 3; p <= 8; ++p) {
            const float* u = &s_u[k][11 - p][0];
            int q = p - 3, mk = 1 << q;
            int bit = (lane >> q) & 1;
            float c0r = bit ? u[6] : u[0];
            float c0i = bit ? u[7] : u[1];
            float c1r = bit ? u[4] : u[2];
            float c1i = bit ? u[5] : u[3];
            #pragma unroll
            for (int r = 0; r < 8; ++r) {
                float px = __shfl_xor(a[r].x, mk, 64);
                float py = __shfl_xor(a[r].y, mk, 64);
                float nx = c0r * a[r].x - c0i * a[r].y + c1r * px - c1i * py;
                float ny = c0r * a[r].y + c0i * a[r].x + c1r * py + c1i * px;
                a[r].x = nx; a[r].y = ny;
            }
        }

        // transpose A->B
        #pragma unroll
        for (int r = 0; r < 8; ++r) buf0[baseA + (r ^ cA)] = a[r];
        __syncthreads();                                   // B1
        #pragma unroll
        for (int rb = 0; rb < 8; ++rb) a[rb] = buf0[(rb << 9) | baseB];

        // gates on former wave bits (wires 2,1,0), now register bits
        REG_GATE(0, 2)
        REG_GATE(1, 1)
        REG_GATE(2, 0)

        // expvals PRE-scatter. Post-ring sign for wire w at source index jp
        // is prefix-XOR P_w of jp bits from 11 downward. rb-combinations:
        float pr[8];
        #pragma unroll
        for (int r = 0; r < 8; ++r)
            pr[r] = a[r].x * a[r].x + a[r].y * a[r].y;
        // wire1: sign rb2^rb1 (+{0,1,6,7})
        float r1 = (pr[0] + pr[1] + pr[6] + pr[7]) - (pr[2] + pr[3] + pr[4] + pr[5]);
        // D: sign parity(rb) (+{0,3,5,6}) — wire2 and factor for wires 3..11
        float D  = (pr[0] + pr[3] + pr[5] + pr[6]) - (pr[1] + pr[2] + pr[4] + pr[7]);
        // D0: sign rb1^rb0 (+{0,3,4,7}) — wire0 factor
        float D0 = (pr[0] + pr[3] + pr[4] + pr[7]) - (pr[1] + pr[2] + pr[5] + pr[6]);
        float r2 = D, r3 = D, r4 = D, r5 = D, r6 = D, r7 = D, r8 = D, r0 = D0;
        // sign-butterfly: rK signed at lane-bit levels per prefix structure
        BF_PLAIN(r1,32) BF_PLAIN(r2,32) BF_SIGN(r3,32) BF_SIGN(r4,32)
        BF_SIGN(r5,32)  BF_SIGN(r6,32)  BF_SIGN(r7,32) BF_SIGN(r8,32) BF_SIGN(r0,32)
        BF_PLAIN(r1,16) BF_PLAIN(r2,16) BF_PLAIN(r3,16) BF_SIGN(r4,16)
        BF_SIGN(r5,16)  BF_SIGN(r6,16)  BF_SIGN(r7,16) BF_SIGN(r8,16) BF_SIGN(r0,16)
        BF_PLAIN(r1,8)  BF_PLAIN(r2,8)  BF_PLAIN(r3,8) BF_PLAIN(r4,8)
        BF_SIGN(r5,8)   BF_SIGN(r6,8)   BF_SIGN(r7,8)  BF_SIGN(r8,8)  BF_SIGN(r0,8)
        BF_PLAIN(r1,4)  BF_PLAIN(r2,4)  BF_PLAIN(r3,4) BF_PLAIN(r4,4)
        BF_PLAIN(r5,4)  BF_SIGN(r6,4)   BF_SIGN(r7,4)  BF_SIGN(r8,4)  BF_SIGN(r0,4)
        BF_PLAIN(r1,2)  BF_PLAIN(r2,2)  BF_PLAIN(r3,2) BF_PLAIN(r4,2)
        BF_PLAIN(r5,2)  BF_PLAIN(r6,2)  BF_SIGN(r7,2)  BF_SIGN(r8,2)  BF_SIGN(r0,2)
        BF_PLAIN(r1,1)  BF_PLAIN(r2,1)  BF_PLAIN(r3,1) BF_PLAIN(r4,1)
        BF_PLAIN(r5,1)  BF_PLAIN(r6,1)  BF_PLAIN(r7,1) BF_SIGN(r8,1)  BF_SIGN(r0,1)
        if (lane == 0) {
            float* sr = s_red[wave];
            sr[0]  = wvp  ? -r0 : r0;
            sr[1]  = r1;  sr[2] = r2;  sr[3] = r3;  sr[4] = r4;
            sr[5]  = r5;  sr[6] = r6;  sr[7] = r7;  sr[8] = r8;
            sr[9]  = wv2  ? -r8 : r8;
            sr[10] = wv21 ? -r8 : r8;
            sr[11] = wvp  ? -r8 : r8;
        }

        // CNOT-ring permutation scatter back to layout A
        #pragma unroll
        for (int rb = 0; rb < 8; ++rb) buf1[idxP[rb]] = a[rb];
        __syncthreads();                                   // B2
        #pragma unroll
        for (int r = 0; r < 8; ++r) a[r] = buf1[baseA + (r ^ cA)];

        // finalize readouts + head (overlaps next step's gates on other waves)
        if (tid < NQ) {
            float s = 0.f;
            #pragma unroll
            for (int w2 = 0; w2 < 8; ++w2) s += s_red[w2][tid];
            readouts[(k * BB + b) * NQ + tid] = s;
        }
        if (tid < 8) {
            float acc2 = s_hb[tid];
            #pragma unroll
            for (int i = 0; i < NQ; ++i) {
                float si = 0.f;
                #pragma unroll
                for (int w2 = 0; w2 < 8; ++w2) si += s_red[w2][i];
                acc2 = fmaf(si, s_hw[tid * NQ + i], acc2);
            }
            logits[(k * BB + b) * 8 + tid] = acc2;
            if (k == KS - 1) last[b * 8 + tid] = acc2;
        }
    }
}

extern "C" void kernel_launch(void* const* d_in, const int* in_sizes, int n_in,
                              void* d_out, int out_size, void* d_ws, size_t ws_size,
                              hipStream_t stream) {
    const int*   ids   = (const int*)d_in[0];
    const int*   mask  = (const int*)d_in[1];
    const float* emb   = (const float*)d_in[2];
    const float* pw    = (const float*)d_in[3];
    const float* pb    = (const float*)d_in[4];
    const float* theta = (const float*)d_in[5];
    const float* hw    = (const float*)d_in[6];
    const float* hb    = (const float*)d_in[7];
    float* out = (float*)d_out;

    float* readouts = out + KS * BB * 8;              // [K,B,NQ]
    float* last     = out + KS * BB * 8 + KS * BB * NQ;

    fused_kernel<<<BB, 512, 0, stream>>>(ids, mask, emb, pw, pb, theta,
                                         hw, hb, readouts, out, last);
}

// Round 4
// 141.722 us; speedup vs baseline: 1.4823x; 1.0283x over previous
//
#include <hip/hip_runtime.h>
#include <math.h>

#define NQ 12
#define DIM 4096
#define KS 6
#define BB 256
#define SEQ 128
#define DEMB 512

// Fused: encoder (embed->pool->tanh proj), 6-step VQC statevector sim,
// per-step Z-expvals and head. One block per sample, 512 threads.
//
// State layout A: j = tid*8 + r (bits 0-2 = reg, 3-8 = lane, 9-11 = wave).
// Layout B: j = rb*512 + lane*8 + wave (bits 9-11 = reg).
// LDS physical address: phys(j) = j ^ ((j>>4)&15)  — spreads lane bits into
// bank bits; all four access patterns (A-write, B-read, ring-scatter-write,
// A-read) are provably conflict-free under this map.

#define REG_GATE(P, W) { \
    const float* u = &s_u[k][W][0]; \
    float u00r=u[0],u00i=u[1],u01r=u[2],u01i=u[3]; \
    float u10r=u[4],u10i=u[5],u11r=u[6],u11i=u[7]; \
    _Pragma("unroll") \
    for (int r0 = 0; r0 < 8; ++r0) if (!(r0 & (1 << (P)))) { \
        int r1 = r0 | (1 << (P)); \
        float2 A = a[r0], Bv = a[r1]; \
        a[r0].x = u00r*A.x - u00i*A.y + u01r*Bv.x - u01i*Bv.y; \
        a[r0].y = u00r*A.y + u00i*A.x + u01r*Bv.y + u01i*Bv.x; \
        a[r1].x = u10r*A.x - u10i*A.y + u11r*Bv.x - u11i*Bv.y; \
        a[r1].y = u10r*A.y + u10i*A.x + u11r*Bv.y + u11i*Bv.x; \
    } }

#define BF_PLAIN(v, m) { float p_ = __shfl_xor(v, m, 64); v = v + p_; }
#define BF_SIGN(v, m)  { float p_ = __shfl_xor(v, m, 64); float d_ = v - p_; \
                         v = (lane & m) ? -d_ : d_; }

__global__ __launch_bounds__(512) void fused_kernel(
    const int* __restrict__ ids, const int* __restrict__ mask,
    const float* __restrict__ emb, const float* __restrict__ pw,
    const float* __restrict__ pb, const float* __restrict__ theta,
    const float* __restrict__ hw, const float* __restrict__ hb,
    float* __restrict__ readouts, float* __restrict__ logits,
    float* __restrict__ last)
{
    __shared__ float2 buf0[DIM];          // 32 KB (also enc s_part)
    __shared__ float2 buf1[DIM];          // 32 KB (also enc s_ids/s_m)
    __shared__ float  s_u[KS][NQ][8];     // fused gate matrices, all steps
    __shared__ float  s_red[8][NQ];
    __shared__ float  s_msum[4];
    __shared__ float  s_wred[2][NQ];
    __shared__ float  s_x[NQ];
    __shared__ float  s_hw[8 * NQ];
    __shared__ float  s_hb[8];

    int b = blockIdx.x;
    int tid = threadIdx.x;
    int lane = tid & 63, wave = tid >> 6;

    // ---------------- encoder phase ----------------
    int*    s_ids = (int*)buf1;
    float*  s_m   = (float*)buf1 + SEQ;
    float4* s_part = (float4*)buf0;       // [4][128]

    if (tid < SEQ) {
        s_ids[tid] = ids[b * SEQ + tid];
        s_m[tid]   = (float)mask[b * SEQ + tid];
    }
    if (tid >= 256 && tid < 256 + 8 * NQ) s_hw[tid - 256] = hw[tid - 256];
    if (tid >= 384 && tid < 392)          s_hb[tid - 384] = hb[tid - 384];
    __syncthreads();

    {
        int g = tid >> 7, e = tid & 127;
        float4 acc = make_float4(0.f, 0.f, 0.f, 0.f);
        float msum = 0.f;
        #pragma unroll 4
        for (int s = g; s < SEQ; s += 4) {
            float m = s_m[s];
            float4 v = ((const float4*)emb)[(size_t)s_ids[s] * 128 + e];
            acc.x = fmaf(m, v.x, acc.x);
            acc.y = fmaf(m, v.y, acc.y);
            acc.z = fmaf(m, v.z, acc.z);
            acc.w = fmaf(m, v.w, acc.w);
            msum += m;
        }
        __syncthreads();   // s_ids/s_m reads done before buf0 overlay write
        s_part[g * 128 + e] = acc;
        if (e == 0) s_msum[g] = msum;
    }
    __syncthreads();

    if (tid < 128) {
        float tm = fmaxf(s_msum[0] + s_msum[1] + s_msum[2] + s_msum[3], 1.f);
        float inv = 1.f / tm;
        float4 p0 = s_part[0 * 128 + tid], p1 = s_part[1 * 128 + tid];
        float4 p2 = s_part[2 * 128 + tid], p3 = s_part[3 * 128 + tid];
        float4 p;
        p.x = (p0.x + p1.x + p2.x + p3.x) * inv;
        p.y = (p0.y + p1.y + p2.y + p3.y) * inv;
        p.z = (p0.z + p1.z + p2.z + p3.z) * inv;
        p.w = (p0.w + p1.w + p2.w + p3.w) * inv;
        float z[NQ];
        #pragma unroll
        for (int i = 0; i < NQ; ++i) {
            float4 w4 = ((const float4*)pw)[i * 128 + tid];
            z[i] = p.x * w4.x + p.y * w4.y + p.z * w4.z + p.w * w4.w;
        }
        #pragma unroll
        for (int i = 0; i < NQ; ++i) {
            #pragma unroll
            for (int off = 32; off > 0; off >>= 1)
                z[i] += __shfl_xor(z[i], off, 64);
        }
        if ((tid & 63) == 0) {
            int w = tid >> 6;
            #pragma unroll
            for (int i = 0; i < NQ; ++i) s_wred[w][i] = z[i];
        }
    }
    __syncthreads();
    if (tid < NQ) {
        float d = pb[tid] + s_wred[0][tid] + s_wred[1][tid];
        s_x[tid] = tanhf(d) * 3.14159274101257324f;
    }
    __syncthreads();

    // ---------------- gate matrices: U = Rot(phi,te,om) @ RY(x) ----------
    if (tid < KS * NQ) {
        int k = tid / NQ, w = tid % NQ;
        float ang = s_x[w];
        float cy = cosf(0.5f * ang), sy = sinf(0.5f * ang);
        const float* th = theta + (k * NQ + w) * 3;
        float phi = th[0], te = th[1], om = th[2];
        float ct = cosf(0.5f * te), st = sinf(0.5f * te);
        float a1 = -0.5f * (phi + om);
        float epr = cosf(a1), epi = sinf(a1);
        float a2 = 0.5f * (phi - om);
        float emr = cosf(a2), emi = sinf(a2);
        float R00r = epr * ct,  R00i = epi * ct;
        float R01r = -emr * st, R01i = -emi * st;
        float R10r = emr * st,  R10i = -emi * st;
        float R11r = epr * ct,  R11i = -epi * ct;
        s_u[k][w][0] =  R00r * cy + R01r * sy;
        s_u[k][w][1] =  R00i * cy + R01i * sy;
        s_u[k][w][2] = -R00r * sy + R01r * cy;
        s_u[k][w][3] = -R00i * sy + R01i * cy;
        s_u[k][w][4] =  R10r * cy + R11r * sy;
        s_u[k][w][5] =  R10i * cy + R11i * sy;
        s_u[k][w][6] = -R10r * sy + R11r * cy;
        s_u[k][w][7] = -R10i * sy + R11i * cy;
    }

    // ---------------- constant addresses (bank-conflict-free swizzle) -----
    // phys(j) = j ^ ((j>>4)&15)
    int baseWA = (tid << 3) ^ ((tid >> 1) & 15);              // layout A base
    int baseRB = ((lane << 3) | wave) ^ ((lane >> 1) & 15);   // layout B base
    int idxP[8];                          // ring-perm targets (swizzled)
    #pragma unroll
    for (int rb = 0; rb < 8; ++rb) {
        int jp = (rb << 9) | (lane << 3) | wave;
        int b0 = (jp >> 11) & 1;
        int pref = b0, outv = 0;
        for (int w = 1; w < NQ; ++w) {
            pref ^= (jp >> (11 - w)) & 1;
            outv |= pref << (11 - w);
        }
        outv |= (b0 ^ pref) << 11;
        idxP[rb] = outv ^ ((outv >> 4) & 15);
    }
    int wv2 = (wave >> 2) & 1, wv21 = ((wave >> 2) ^ (wave >> 1)) & 1;
    int wvp = ((wave >> 2) ^ (wave >> 1) ^ wave) & 1;   // parity(wave)

    float2 a[8];
    #pragma unroll
    for (int r = 0; r < 8; ++r) a[r] = make_float2(0.f, 0.f);
    if (tid == 0) a[0].x = 1.f;
    __syncthreads();   // s_u ready, buf reads done

    // ---------------- K steps ----------------
    for (int k = 0; k < KS; ++k) {
        // gates on register bits (wires 11,10,9), layout A
        REG_GATE(0, 11)
        REG_GATE(1, 10)
        REG_GATE(2, 9)

        // gates on lane bits (wires 8..3)
        #pragma unroll
        for (int p = 3; p <= 8; ++p) {
            const float* u = &s_u[k][11 - p][0];
            int q = p - 3, mk = 1 << q;
            int bit = (lane >> q) & 1;
            float c0r = bit ? u[6] : u[0];
            float c0i = bit ? u[7] : u[1];
            float c1r = bit ? u[4] : u[2];
            float c1i = bit ? u[5] : u[3];
            #pragma unroll
            for (int r = 0; r < 8; ++r) {
                float px = __shfl_xor(a[r].x, mk, 64);
                float py = __shfl_xor(a[r].y, mk, 64);
                float nx = c0r * a[r].x - c0i * a[r].y + c1r * px - c1i * py;
                float ny = c0r * a[r].y + c0i * a[r].x + c1r * py + c1i * px;
                a[r].x = nx; a[r].y = ny;
            }
        }

        // transpose A->B
        #pragma unroll
        for (int r = 0; r < 8; ++r) buf0[baseWA ^ r] = a[r];
        __syncthreads();                                   // B1
        #pragma unroll
        for (int rb = 0; rb < 8; ++rb) a[rb] = buf0[(rb << 9) | baseRB];

        // gates on former wave bits (wires 2,1,0), now register bits
        REG_GATE(0, 2)
        REG_GATE(1, 1)
        REG_GATE(2, 0)

        // expvals PRE-scatter. Post-ring sign for wire w at source index jp
        // is prefix-XOR of jp bits; factorized into rb-combos + sign-butterfly
        float pr[8];
        #pragma unroll
        for (int r = 0; r < 8; ++r)
            pr[r] = a[r].x * a[r].x + a[r].y * a[r].y;
        float r1 = (pr[0] + pr[1] + pr[6] + pr[7]) - (pr[2] + pr[3] + pr[4] + pr[5]);
        float D  = (pr[0] + pr[3] + pr[5] + pr[6]) - (pr[1] + pr[2] + pr[4] + pr[7]);
        float D0 = (pr[0] + pr[3] + pr[4] + pr[7]) - (pr[1] + pr[2] + pr[5] + pr[6]);
        float r2 = D, r3 = D, r4 = D, r5 = D, r6 = D, r7 = D, r8 = D, r0 = D0;
        BF_PLAIN(r1,32) BF_PLAIN(r2,32) BF_SIGN(r3,32) BF_SIGN(r4,32)
        BF_SIGN(r5,32)  BF_SIGN(r6,32)  BF_SIGN(r7,32) BF_SIGN(r8,32) BF_SIGN(r0,32)
        BF_PLAIN(r1,16) BF_PLAIN(r2,16) BF_PLAIN(r3,16) BF_SIGN(r4,16)
        BF_SIGN(r5,16)  BF_SIGN(r6,16)  BF_SIGN(r7,16) BF_SIGN(r8,16) BF_SIGN(r0,16)
        BF_PLAIN(r1,8)  BF_PLAIN(r2,8)  BF_PLAIN(r3,8) BF_PLAIN(r4,8)
        BF_SIGN(r5,8)   BF_SIGN(r6,8)   BF_SIGN(r7,8)  BF_SIGN(r8,8)  BF_SIGN(r0,8)
        BF_PLAIN(r1,4)  BF_PLAIN(r2,4)  BF_PLAIN(r3,4) BF_PLAIN(r4,4)
        BF_PLAIN(r5,4)  BF_SIGN(r6,4)   BF_SIGN(r7,4)  BF_SIGN(r8,4)  BF_SIGN(r0,4)
        BF_PLAIN(r1,2)  BF_PLAIN(r2,2)  BF_PLAIN(r3,2) BF_PLAIN(r4,2)
        BF_PLAIN(r5,2)  BF_PLAIN(r6,2)  BF_SIGN(r7,2)  BF_SIGN(r8,2)  BF_SIGN(r0,2)
        BF_PLAIN(r1,1)  BF_PLAIN(r2,1)  BF_PLAIN(r3,1) BF_PLAIN(r4,1)
        BF_PLAIN(r5,1)  BF_PLAIN(r6,1)  BF_PLAIN(r7,1) BF_SIGN(r8,1)  BF_SIGN(r0,1)
        if (lane == 0) {
            float* sr = s_red[wave];
            sr[0]  = wvp  ? -r0 : r0;
            sr[1]  = r1;  sr[2] = r2;  sr[3] = r3;  sr[4] = r4;
            sr[5]  = r5;  sr[6] = r6;  sr[7] = r7;  sr[8] = r8;
            sr[9]  = wv2  ? -r8 : r8;
            sr[10] = wv21 ? -r8 : r8;
            sr[11] = wvp  ? -r8 : r8;
        }

        // CNOT-ring permutation scatter back to layout A
        #pragma unroll
        for (int rb = 0; rb < 8; ++rb) buf1[idxP[rb]] = a[rb];
        __syncthreads();                                   // B2
        #pragma unroll
        for (int r = 0; r < 8; ++r) a[r] = buf1[baseWA ^ r];

        // finalize readouts + head (overlaps next step's gates on other waves)
        if (tid < NQ) {
            float s = 0.f;
            #pragma unroll
            for (int w2 = 0; w2 < 8; ++w2) s += s_red[w2][tid];
            readouts[(k * BB + b) * NQ + tid] = s;
        }
        if (tid < 8) {
            float acc2 = s_hb[tid];
            #pragma unroll
            for (int i = 0; i < NQ; ++i) {
                float si = 0.f;
                #pragma unroll
                for (int w2 = 0; w2 < 8; ++w2) si += s_red[w2][i];
                acc2 = fmaf(si, s_hw[tid * NQ + i], acc2);
            }
            logits[(k * BB + b) * 8 + tid] = acc2;
            if (k == KS - 1) last[b * 8 + tid] = acc2;
        }
    }
}

extern "C" void kernel_launch(void* const* d_in, const int* in_sizes, int n_in,
                              void* d_out, int out_size, void* d_ws, size_t ws_size,
                              hipStream_t stream) {
    const int*   ids   = (const int*)d_in[0];
    const int*   mask  = (const int*)d_in[1];
    const float* emb   = (const float*)d_in[2];
    const float* pw    = (const float*)d_in[3];
    const float* pb    = (const float*)d_in[4];
    const float* theta = (const float*)d_in[5];
    const float* hw    = (const float*)d_in[6];
    const float* hb    = (const float*)d_in[7];
    float* out = (float*)d_out;

    float* readouts = out + KS * BB * 8;              // [K,B,NQ]
    float* last     = out + KS * BB * 8 + KS * BB * NQ;

    fused_kernel<<<BB, 512, 0, stream>>>(ids, mask, emb, pw, pb, theta,
                                         hw, hb, readouts, out, last);
}